// Round 3
// baseline (276.249 us; speedup 1.0000x reference)
//
#include <hip/hip_runtime.h>
#include <hip/hip_fp16.h>

#define N_SEQ 8192
#define E_DIM 768
#define D_OUT 64
#define PADK 68                       // 64 + 4 pad -> 136B rows: 2-way (free) bank aliasing
#define SCALE_LOG2 0.18033688011112042f   // 1/(8*ln2): fold softmax scale + log2e into Q

typedef __attribute__((ext_vector_type(8)))  short s16x8;
typedef __attribute__((ext_vector_type(4)))  float f32x4;
typedef __attribute__((ext_vector_type(16))) float f32x16;

static __device__ __forceinline__ unsigned short f2bf(float f) {
    union { float f; unsigned int u; } v; v.f = f;
    unsigned int r = v.u + 0x7FFFu + ((v.u >> 16) & 1u);   // RNE
    return (unsigned short)(r >> 16);
}
static __device__ __forceinline__ float bf2f(unsigned short h) {
    union { float f; unsigned int u; } v; v.u = ((unsigned int)h) << 16; return v.f;
}
// packed f16 max on int-punned half2 (ROCm header lacks __hmax2 on this path)
static __device__ __forceinline__ int pkmax_f16(int a, int b) {
    int d;
    asm("v_pk_max_f16 %0, %1, %2" : "=v"(d) : "v"(a), "v"(b));
    return d;
}
static __device__ __forceinline__ s16x8 gfrag(const unsigned short* p) {
    union { uint4 u; s16x8 s; } r; r.u = *(const uint4*)p; return r.s;
}
static __device__ __forceinline__ s16x8 ldsfrag(const unsigned short* p) {
    union { uint2 u[2]; s16x8 s; } r;
    r.u[0] = *(const uint2*)(p);
    r.u[1] = *(const uint2*)(p + 4);
    return r.s;
}
static __device__ __forceinline__ void st32(unsigned short* d, uint4 a, uint4 b) {
    uint2* p = (uint2*)d;
    p[0] = make_uint2(a.x, a.y); p[1] = make_uint2(a.z, a.w);
    p[2] = make_uint2(b.x, b.y); p[3] = make_uint2(b.z, b.w);
}

// ---------------- Kernel 1: W -> Wt (transposed, bf16 hi/lo) -----------------
__global__ __launch_bounds__(256) void prep_w(const float* __restrict__ WQ,
                                              const float* __restrict__ WK,
                                              const float* __restrict__ WV,
                                              unsigned short* __restrict__ Wthi,
                                              unsigned short* __restrict__ Wtlo) {
    int idx = blockIdx.x * 256 + threadIdx.x;          // 192*768 total
    if (idx >= 192 * E_DIM) return;
    int n = idx / E_DIM;
    int k = idx - n * E_DIM;
    float v;
    if (n < 64)       v = WQ[k * 64 + n];
    else if (n < 128) v = WK[k * 64 + (n - 64)];
    else              v = WV[k * 64 + (n - 128)];
    unsigned short hb = f2bf(v);
    Wthi[idx] = hb;
    Wtlo[idx] = f2bf(v - bf2f(hb));
}

// ---------------- Kernel 2: QKV projection (split-bf16, 16x16 tiles) ---------
// C = X[8192x768] @ W[768x192]; 512 m-tiles x 12 n-tiles = 6144 wave-tasks.
__global__ __launch_bounds__(256, 4) void proj_qkv(const float* __restrict__ X,
                                                   const unsigned short* __restrict__ Wthi,
                                                   const unsigned short* __restrict__ Wtlo,
                                                   unsigned short* __restrict__ Qhi,
                                                   unsigned short* __restrict__ Qlo,
                                                   unsigned short* __restrict__ Khi,
                                                   unsigned short* __restrict__ Klo,
                                                   unsigned short* __restrict__ Vt) {
    int tid  = threadIdx.x;
    int wv   = tid >> 6;
    int lane = tid & 63;
    int id   = blockIdx.x * 4 + wv;          // 0..6143
    int mt   = id / 12;
    int nt   = id - mt * 12;
    int m0 = mt * 16, n0 = nt * 16;          // n0 in 0..191
    int lr = lane & 15, lk = lane >> 4;      // row-in-tile, k-quad

    f32x4 acc;
    #pragma unroll
    for (int i = 0; i < 4; ++i) acc[i] = 0.f;

    const float* xbase = X + (size_t)(m0 + lr) * E_DIM + lk * 8;
    const unsigned short* wh = Wthi + (size_t)(n0 + lr) * E_DIM + lk * 8;
    const unsigned short* wl = Wtlo + (size_t)(n0 + lr) * E_DIM + lk * 8;

    #pragma unroll 4
    for (int ks = 0; ks < E_DIM / 32; ++ks) {
        int kb = ks * 32;
        float xv[8];
        *(float4*)(xv)     = *(const float4*)(xbase + kb);
        *(float4*)(xv + 4) = *(const float4*)(xbase + kb + 4);
        s16x8 ah, al;
        #pragma unroll
        for (int j = 0; j < 8; ++j) {
            unsigned short hb = f2bf(xv[j]);
            ah[j] = (short)hb;
            al[j] = (short)f2bf(xv[j] - bf2f(hb));
        }
        s16x8 bh = gfrag(wh + kb);
        s16x8 bl = gfrag(wl + kb);
        acc = __builtin_amdgcn_mfma_f32_16x16x32_bf16(ah, bh, acc, 0, 0, 0);
        acc = __builtin_amdgcn_mfma_f32_16x16x32_bf16(ah, bl, acc, 0, 0, 0);
        acc = __builtin_amdgcn_mfma_f32_16x16x32_bf16(al, bh, acc, 0, 0, 0);
    }

    // C/D layout (16x16): col = lane&15, row = (lane>>4)*4 + r  [verified m89/m91]
    if (n0 < 64) {                       // Q: scale by 1/(8 ln2), split hi/lo
        #pragma unroll
        for (int r = 0; r < 4; ++r) {
            int grow = m0 + lk * 4 + r, gcol = n0 + lr;
            float q = acc[r] * SCALE_LOG2;
            unsigned short hb = f2bf(q);
            Qhi[(size_t)grow * 64 + gcol] = hb;
            Qlo[(size_t)grow * 64 + gcol] = f2bf(q - bf2f(hb));
        }
    } else if (n0 < 128) {               // K: split hi/lo
        #pragma unroll
        for (int r = 0; r < 4; ++r) {
            int grow = m0 + lk * 4 + r, gcol = n0 + lr - 64;
            float v = acc[r];
            unsigned short hb = f2bf(v);
            Khi[(size_t)grow * 64 + gcol] = hb;
            Klo[(size_t)grow * 64 + gcol] = f2bf(v - bf2f(hb));
        }
    } else {                             // V: transposed bf16; 4 consecutive rows -> one 8B store
        ushort4 pk;
        pk.x = f2bf(acc[0]); pk.y = f2bf(acc[1]);
        pk.z = f2bf(acc[2]); pk.w = f2bf(acc[3]);
        int gcol = n0 + lr - 128;
        *(ushort4*)(Vt + (size_t)gcol * N_SEQ + m0 + lk * 4) = pk;
    }
}

// ---------------- Kernel 3: flash attention (split-K over KV) ----------------
// grid (nsplit, 64); block 256 = 4 waves, each wave owns 32 Q-rows.
// LDS: sK[0..63]=Khi rows, sK[64..127]=Klo rows; after S-phase the same region
// is reused for per-wave P tiles (rows wv*32..wv*32+31). sV separate.
__global__ __launch_bounds__(256, 4) void attn(const unsigned short* __restrict__ Qhi,
                                               const unsigned short* __restrict__ Qlo,
                                               const unsigned short* __restrict__ Khi,
                                               const unsigned short* __restrict__ Klo,
                                               const unsigned short* __restrict__ Vt,
                                               float* __restrict__ Opart,
                                               float* __restrict__ mpart,
                                               float* __restrict__ lpart,
                                               int chunk) {
    __shared__ unsigned short sK[128 * PADK];
    __shared__ unsigned short sV [64 * PADK];    // [d][key]

    int tid = threadIdx.x, wv = tid >> 6, lane = tid & 63;
    int lrow = lane & 31, lh = lane >> 5;
    int c = blockIdx.x, qb = blockIdx.y;
    int q0 = qb * 128 + wv * 32;

    // Q fragments (whole D=64) resident in registers
    s16x8 qh[4], ql[4];
    #pragma unroll
    for (int ks = 0; ks < 4; ++ks) {
        int kb = ks * 16 + lh * 8;
        qh[ks] = gfrag(Qhi + (size_t)(q0 + lrow) * 64 + kb);
        ql[ks] = gfrag(Qlo + (size_t)(q0 + lrow) * 64 + kb);
    }

    f32x16 O0, O1, La;
    #pragma unroll
    for (int i = 0; i < 16; ++i) { O0[i] = 0.f; O1[i] = 0.f; La[i] = 0.f; }
    float mrow[16];
    #pragma unroll
    for (int r = 0; r < 16; ++r) mrow[r] = -1e30f;
    s16x8 ones;
    #pragma unroll
    for (int j = 0; j < 8; ++j) ones[j] = (short)0x3F80;   // bf16 1.0

    int steps = chunk >> 6;
    int srow = tid >> 2, sseg = tid & 3;    // staging: 64 rows x 4 segs x 16 elems

    for (int it = 0; it < steps; ++it) {
        int j0 = c * chunk + it * 64;
        __syncthreads();
        {   // stage K hi/lo tiles [64 keys][64 d] and V^T tile [64 d][64 keys]
            const uint4* ps = (const uint4*)(Khi + ((size_t)(j0 + srow) * 64 + sseg * 16));
            st32(sK + srow * PADK + sseg * 16, ps[0], ps[1]);
            ps = (const uint4*)(Klo + ((size_t)(j0 + srow) * 64 + sseg * 16));
            st32(sK + (64 + srow) * PADK + sseg * 16, ps[0], ps[1]);
            ps = (const uint4*)(Vt + ((size_t)srow * N_SEQ + j0 + sseg * 16));
            st32(sV + srow * PADK + sseg * 16, ps[0], ps[1]);
        }
        __syncthreads();

        // S = Qs @ K^T  (3-term split-bf16)
        f32x16 s0, s1;
        #pragma unroll
        for (int i = 0; i < 16; ++i) { s0[i] = 0.f; s1[i] = 0.f; }
        #pragma unroll
        for (int ks = 0; ks < 4; ++ks) {
            int kb = ks * 16 + lh * 8;
            s16x8 b0h = ldsfrag(sK + (size_t)lrow * PADK + kb);
            s16x8 b0l = ldsfrag(sK + (size_t)(64 + lrow) * PADK + kb);
            s0 = __builtin_amdgcn_mfma_f32_32x32x16_bf16(qh[ks], b0h, s0, 0, 0, 0);
            s0 = __builtin_amdgcn_mfma_f32_32x32x16_bf16(qh[ks], b0l, s0, 0, 0, 0);
            s0 = __builtin_amdgcn_mfma_f32_32x32x16_bf16(ql[ks], b0h, s0, 0, 0, 0);
            s16x8 b1h = ldsfrag(sK + (size_t)(32 + lrow) * PADK + kb);
            s16x8 b1l = ldsfrag(sK + (size_t)(96 + lrow) * PADK + kb);
            s1 = __builtin_amdgcn_mfma_f32_32x32x16_bf16(qh[ks], b1h, s1, 0, 0, 0);
            s1 = __builtin_amdgcn_mfma_f32_32x32x16_bf16(qh[ks], b1l, s1, 0, 0, 0);
            s1 = __builtin_amdgcn_mfma_f32_32x32x16_bf16(ql[ks], b1h, s1, 0, 0, 0);
        }

        // row max across 32 key-cols (lanes) via packed-f16 butterfly
        union H2I { __half2 h2; int i; } hmx[8];
        #pragma unroll
        for (int j = 0; j < 8; ++j)
            hmx[j].h2 = __floats2half2_rn(fmaxf(s0[2 * j],     s1[2 * j]),
                                          fmaxf(s0[2 * j + 1], s1[2 * j + 1]));
        #pragma unroll
        for (int msk = 1; msk < 32; msk <<= 1) {
            #pragma unroll
            for (int j = 0; j < 8; ++j) {
                int o = __shfl_xor(hmx[j].i, msk, 64);
                hmx[j].i = pkmax_f16(hmx[j].i, o);
            }
        }
        float alf[16];
        #pragma unroll
        for (int j = 0; j < 8; ++j) {
            float rm0 = __low2float(hmx[j].h2), rm1 = __high2float(hmx[j].h2);
            int r = 2 * j;
            float mn = fmaxf(mrow[r], rm0);
            alf[r] = exp2f(mrow[r] - mn); mrow[r] = mn;
            r = 2 * j + 1;
            mn = fmaxf(mrow[r], rm1);
            alf[r] = exp2f(mrow[r] - mn); mrow[r] = mn;
        }

        // all waves must be done reading K before P overlays it
        __syncthreads();

        // P = exp2(S - m); rescale O,l; write P (bf16) into sK rows [wv*32 ..)
        unsigned short* pp = sK + (size_t)(wv * 32) * PADK;
        #pragma unroll
        for (int r = 0; r < 16; ++r) {
            float p0 = exp2f(s0[r] - mrow[r]);
            float p1 = exp2f(s1[r] - mrow[r]);
            O0[r] *= alf[r]; O1[r] *= alf[r]; La[r] *= alf[r];
            int row = (r & 3) + 8 * (r >> 2) + 4 * lh;
            pp[row * PADK + lrow]      = f2bf(p0);
            pp[row * PADK + 32 + lrow] = f2bf(p1);
        }

        // O += P @ V ; l += P @ 1 (ones-column MFMA replaces shuffle row-sums)
        #pragma unroll
        for (int ks = 0; ks < 4; ++ks) {
            int kb = ks * 16 + lh * 8;
            s16x8 a  = ldsfrag(pp + (size_t)lrow * PADK + kb);
            s16x8 b0 = ldsfrag(sV + (size_t)lrow * PADK + kb);
            s16x8 b1 = ldsfrag(sV + (size_t)(32 + lrow) * PADK + kb);
            O0 = __builtin_amdgcn_mfma_f32_32x32x16_bf16(a, b0,   O0, 0, 0, 0);
            O1 = __builtin_amdgcn_mfma_f32_32x32x16_bf16(a, b1,   O1, 0, 0, 0);
            La = __builtin_amdgcn_mfma_f32_32x32x16_bf16(a, ones, La, 0, 0, 0);
        }
    }

    // store partials
    #pragma unroll
    for (int r = 0; r < 16; ++r) {
        int row = (r & 3) + 8 * (r >> 2) + 4 * lh;
        int grow = q0 + row;
        size_t ob = ((size_t)c * N_SEQ + grow) * 64;
        Opart[ob + lrow]      = O0[r];
        Opart[ob + 32 + lrow] = O1[r];
        if (lrow == 0) {
            mpart[c * N_SEQ + grow] = mrow[r];
            lpart[c * N_SEQ + grow] = La[r];
        }
    }
}

// ---------------- Kernel 4: combine split-K partials -------------------------
__global__ __launch_bounds__(256) void combine(const float* __restrict__ Opart,
                                               const float* __restrict__ mpart,
                                               const float* __restrict__ lpart,
                                               float* __restrict__ out,
                                               int nsplit) {
    int idx = blockIdx.x * 256 + threadIdx.x;    // N_SEQ*64
    int row = idx >> 6, d = idx & 63;
    float M = -1e30f;
    for (int c = 0; c < nsplit; ++c) M = fmaxf(M, mpart[c * N_SEQ + row]);
    float num = 0.f, den = 0.f;
    for (int c = 0; c < nsplit; ++c) {
        float w = exp2f(mpart[c * N_SEQ + row] - M);
        den += w * lpart[c * N_SEQ + row];
        num += w * Opart[((size_t)c * N_SEQ + row) * 64 + d];
    }
    out[idx] = num / den;
}

extern "C" void kernel_launch(void* const* d_in, const int* in_sizes, int n_in,
                              void* d_out, int out_size, void* d_ws, size_t ws_size,
                              hipStream_t stream) {
    const float* X  = (const float*)d_in[0];
    const float* WQ = (const float*)d_in[1];
    const float* WK = (const float*)d_in[2];
    const float* WV = (const float*)d_in[3];
    float* out = (float*)d_out;

    // workspace carve
    const size_t szQK = (size_t)N_SEQ * 64 * 2;      // 1 MB each (bf16)
    const size_t szW  = (size_t)192 * E_DIM * 2;     // 288 KB each
    char* p = (char*)d_ws;
    unsigned short* Qhi = (unsigned short*)p; p += szQK;
    unsigned short* Qlo = (unsigned short*)p; p += szQK;
    unsigned short* Khi = (unsigned short*)p; p += szQK;
    unsigned short* Klo = (unsigned short*)p; p += szQK;
    unsigned short* Vt  = (unsigned short*)p; p += szQK;
    unsigned short* Wthi = (unsigned short*)p; p += szW;
    unsigned short* Wtlo = (unsigned short*)p; p += szW;
    size_t base = (size_t)(p - (char*)d_ws);
    size_t per  = (size_t)N_SEQ * 64 * 4 + 2 * (size_t)N_SEQ * 4;  // Opart + m + l per split
    int nsplit = 16;
    while (nsplit > 1 && base + (size_t)nsplit * per > ws_size) nsplit >>= 1;
    float* mpart = (float*)p; p += (size_t)nsplit * N_SEQ * 4;
    float* lpart = (float*)p; p += (size_t)nsplit * N_SEQ * 4;
    float* Opart = (float*)p;

    int chunk = N_SEQ / nsplit;

    prep_w<<<(192 * E_DIM + 255) / 256, 256, 0, stream>>>(WQ, WK, WV, Wthi, Wtlo);
    proj_qkv<<<1536, 256, 0, stream>>>(X, Wthi, Wtlo, Qhi, Qlo, Khi, Klo, Vt);
    attn<<<dim3(nsplit, N_SEQ / 128), 256, 0, stream>>>(Qhi, Qlo, Khi, Klo, Vt,
                                                        Opart, mpart, lpart, chunk);
    combine<<<(N_SEQ * 64 + 255) / 256, 256, 0, stream>>>(Opart, mpart, lpart, out, nsplit);
}

// Round 4
// 221.801 us; speedup vs baseline: 1.2455x; 1.2455x over previous
//
#include <hip/hip_runtime.h>
#include <hip/hip_fp16.h>

#define N_SEQ 8192
#define E_DIM 768
#define D_OUT 64
#define PADK 68                       // 64 + 4 pad -> 136B rows: 2-way (free) bank aliasing
#define SCALE_LOG2 0.18033688011112042f   // 1/(8*ln2): fold softmax scale + log2e into Q

typedef __attribute__((ext_vector_type(8)))  short s16x8;
typedef __attribute__((ext_vector_type(4)))  float f32x4;
typedef __attribute__((ext_vector_type(16))) float f32x16;

static __device__ __forceinline__ unsigned short f2bf(float f) {
    union { float f; unsigned int u; } v; v.f = f;
    unsigned int r = v.u + 0x7FFFu + ((v.u >> 16) & 1u);   // RNE
    return (unsigned short)(r >> 16);
}
static __device__ __forceinline__ float bf2f(unsigned short h) {
    union { float f; unsigned int u; } v; v.u = ((unsigned int)h) << 16; return v.f;
}
// truncating f32->bf16 (1 op). Bias cancels where numerator/denominator share P.
static __device__ __forceinline__ unsigned short f2bf_trunc(float f) {
    union { float f; unsigned int u; } v; v.f = f;
    return (unsigned short)(v.u >> 16);
}
// packed f16 max on int-punned half2 (ROCm header lacks __hmax2 on this path)
static __device__ __forceinline__ int pkmax_f16(int a, int b) {
    int d;
    asm("v_pk_max_f16 %0, %1, %2" : "=v"(d) : "v"(a), "v"(b));
    return d;
}
static __device__ __forceinline__ s16x8 gfrag(const unsigned short* p) {
    union { uint4 u; s16x8 s; } r; r.u = *(const uint4*)p; return r.s;
}
static __device__ __forceinline__ s16x8 ldsfrag(const unsigned short* p) {
    union { uint2 u[2]; s16x8 s; } r;
    r.u[0] = *(const uint2*)(p);
    r.u[1] = *(const uint2*)(p + 4);
    return r.s;
}
static __device__ __forceinline__ void st32(unsigned short* d, uint4 a, uint4 b) {
    uint2* p = (uint2*)d;
    p[0] = make_uint2(a.x, a.y); p[1] = make_uint2(a.z, a.w);
    p[2] = make_uint2(b.x, b.y); p[3] = make_uint2(b.z, b.w);
}

// ---------------- Kernel 1a: W -> Wt (transposed, bf16 hi/lo) ----------------
__global__ __launch_bounds__(256) void prep_w(const float* __restrict__ WQ,
                                              const float* __restrict__ WK,
                                              const float* __restrict__ WV,
                                              unsigned short* __restrict__ Wthi,
                                              unsigned short* __restrict__ Wtlo) {
    int idx = blockIdx.x * 256 + threadIdx.x;          // 192*768 total
    if (idx >= 192 * E_DIM) return;
    int n = idx / E_DIM;
    int k = idx - n * E_DIM;
    float v;
    if (n < 64)       v = WQ[k * 64 + n];
    else if (n < 128) v = WK[k * 64 + (n - 64)];
    else              v = WV[k * 64 + (n - 128)];
    unsigned short hb = f2bf(v);
    Wthi[idx] = hb;
    Wtlo[idx] = f2bf(v - bf2f(hb));
}

// ---------------- Kernel 1b: X -> bf16 hi/lo (coalesced, BW-bound) -----------
__global__ __launch_bounds__(256) void prep_x(const float* __restrict__ X,
                                              unsigned short* __restrict__ Xhi,
                                              unsigned short* __restrict__ Xlo) {
    int idx = blockIdx.x * 256 + threadIdx.x;          // over float4: 8192*768/4
    float4 v = ((const float4*)X)[idx];
    ushort4 hi, lo;
    hi.x = f2bf(v.x); lo.x = f2bf(v.x - bf2f(hi.x));
    hi.y = f2bf(v.y); lo.y = f2bf(v.y - bf2f(hi.y));
    hi.z = f2bf(v.z); lo.z = f2bf(v.z - bf2f(hi.z));
    hi.w = f2bf(v.w); lo.w = f2bf(v.w - bf2f(hi.w));
    ((ushort4*)Xhi)[idx] = hi;
    ((ushort4*)Xlo)[idx] = lo;
}

// ---------------- Kernel 2: QKV projection (pre-split bf16, 16x16 tiles) -----
// C = X[8192x768] @ W[768x192]; 512 m-tiles x 12 n-tiles = 6144 wave-tasks.
__global__ __launch_bounds__(256, 4) void proj_qkv(const unsigned short* __restrict__ Xhi,
                                                   const unsigned short* __restrict__ Xlo,
                                                   const unsigned short* __restrict__ Wthi,
                                                   const unsigned short* __restrict__ Wtlo,
                                                   unsigned short* __restrict__ Qhi,
                                                   unsigned short* __restrict__ Qlo,
                                                   unsigned short* __restrict__ Khi,
                                                   unsigned short* __restrict__ Klo,
                                                   unsigned short* __restrict__ Vt) {
    int tid  = threadIdx.x;
    int wv   = tid >> 6;
    int lane = tid & 63;
    int id   = blockIdx.x * 4 + wv;          // 0..6143
    int mt   = id / 12;
    int nt   = id - mt * 12;
    int m0 = mt * 16, n0 = nt * 16;          // n0 in 0..191
    int lr = lane & 15, lk = lane >> 4;      // row-in-tile, k-quad

    f32x4 acc;
    #pragma unroll
    for (int i = 0; i < 4; ++i) acc[i] = 0.f;

    const unsigned short* xh = Xhi  + (size_t)(m0 + lr) * E_DIM + lk * 8;
    const unsigned short* xl = Xlo  + (size_t)(m0 + lr) * E_DIM + lk * 8;
    const unsigned short* wh = Wthi + (size_t)(n0 + lr) * E_DIM + lk * 8;
    const unsigned short* wl = Wtlo + (size_t)(n0 + lr) * E_DIM + lk * 8;

    if (nt < 8) {                            // Q / K: 3-term split product
        #pragma unroll 4
        for (int ks = 0; ks < E_DIM / 32; ++ks) {
            int kb = ks * 32;
            s16x8 ah = gfrag(xh + kb);
            s16x8 al = gfrag(xl + kb);
            s16x8 bh = gfrag(wh + kb);
            s16x8 bl = gfrag(wl + kb);
            acc = __builtin_amdgcn_mfma_f32_16x16x32_bf16(ah, bh, acc, 0, 0, 0);
            acc = __builtin_amdgcn_mfma_f32_16x16x32_bf16(ah, bl, acc, 0, 0, 0);
            acc = __builtin_amdgcn_mfma_f32_16x16x32_bf16(al, bh, acc, 0, 0, 0);
        }
        // C/D layout (16x16): col = lane&15, row = (lane>>4)*4 + r  [m89/m91]
        if (n0 < 64) {                       // Q: scale by 1/(8 ln2), split hi/lo
            #pragma unroll
            for (int r = 0; r < 4; ++r) {
                int grow = m0 + lk * 4 + r, gcol = n0 + lr;
                float q = acc[r] * SCALE_LOG2;
                unsigned short hb = f2bf(q);
                Qhi[(size_t)grow * 64 + gcol] = hb;
                Qlo[(size_t)grow * 64 + gcol] = f2bf(q - bf2f(hb));
            }
        } else {                             // K: split hi/lo
            #pragma unroll
            for (int r = 0; r < 4; ++r) {
                int grow = m0 + lk * 4 + r, gcol = n0 + lr - 64;
                float v = acc[r];
                unsigned short hb = f2bf(v);
                Khi[(size_t)grow * 64 + gcol] = hb;
                Klo[(size_t)grow * 64 + gcol] = f2bf(v - bf2f(hb));
            }
        }
    } else {                                 // V: hi-only product (err ~0.1 ok)
        #pragma unroll 4
        for (int ks = 0; ks < E_DIM / 32; ++ks) {
            int kb = ks * 32;
            s16x8 ah = gfrag(xh + kb);
            s16x8 bh = gfrag(wh + kb);
            acc = __builtin_amdgcn_mfma_f32_16x16x32_bf16(ah, bh, acc, 0, 0, 0);
        }
        ushort4 pk;                          // 4 consecutive rows -> one 8B store
        pk.x = f2bf(acc[0]); pk.y = f2bf(acc[1]);
        pk.z = f2bf(acc[2]); pk.w = f2bf(acc[3]);
        int gcol = n0 + lr - 128;
        *(ushort4*)(Vt + (size_t)gcol * N_SEQ + m0 + lk * 4) = pk;
    }
}

// ---------------- Kernel 3: flash attention (split-K over KV) ----------------
// grid (nsplit, 64); block 256 = 4 waves, each wave owns 32 Q-rows.
// LDS: sK[0..63]=Khi rows, sK[64..127]=Klo rows; after the S-phase the region
// is overlaid with per-wave P tiles. sV separate. (256,3): ~158 unified regs
// fits the 3-waves/EU cap -> 12 waves/CU, no spill (R3's (256,4) spilled).
__global__ __launch_bounds__(256, 3) void attn(const unsigned short* __restrict__ Qhi,
                                               const unsigned short* __restrict__ Qlo,
                                               const unsigned short* __restrict__ Khi,
                                               const unsigned short* __restrict__ Klo,
                                               const unsigned short* __restrict__ Vt,
                                               float* __restrict__ Opart,
                                               float* __restrict__ mpart,
                                               float* __restrict__ lpart,
                                               int chunk) {
    __shared__ unsigned short sK[128 * PADK];
    __shared__ unsigned short sV [64 * PADK];    // [d][key]

    int tid = threadIdx.x, wv = tid >> 6, lane = tid & 63;
    int lrow = lane & 31, lh = lane >> 5;
    int c = blockIdx.x, qb = blockIdx.y;
    int q0 = qb * 128 + wv * 32;

    // Q fragments (whole D=64) resident in registers
    s16x8 qh[4], ql[4];
    #pragma unroll
    for (int ks = 0; ks < 4; ++ks) {
        int kb = ks * 16 + lh * 8;
        qh[ks] = gfrag(Qhi + (size_t)(q0 + lrow) * 64 + kb);
        ql[ks] = gfrag(Qlo + (size_t)(q0 + lrow) * 64 + kb);
    }

    f32x16 O0, O1, La;
    #pragma unroll
    for (int i = 0; i < 16; ++i) { O0[i] = 0.f; O1[i] = 0.f; La[i] = 0.f; }
    float mrow[16];
    #pragma unroll
    for (int r = 0; r < 16; ++r) mrow[r] = -1e30f;
    s16x8 ones;
    #pragma unroll
    for (int j = 0; j < 8; ++j) ones[j] = (short)0x3F80;   // bf16 1.0

    int steps = chunk >> 6;
    int srow = tid >> 2, sseg = tid & 3;    // staging: 64 rows x 4 segs x 16 elems

    for (int it = 0; it < steps; ++it) {
        int j0 = c * chunk + it * 64;
        __syncthreads();
        {   // stage K hi/lo tiles [64 keys][64 d] and V^T tile [64 d][64 keys]
            const uint4* ps = (const uint4*)(Khi + ((size_t)(j0 + srow) * 64 + sseg * 16));
            st32(sK + srow * PADK + sseg * 16, ps[0], ps[1]);
            ps = (const uint4*)(Klo + ((size_t)(j0 + srow) * 64 + sseg * 16));
            st32(sK + (64 + srow) * PADK + sseg * 16, ps[0], ps[1]);
            ps = (const uint4*)(Vt + ((size_t)srow * N_SEQ + j0 + sseg * 16));
            st32(sV + srow * PADK + sseg * 16, ps[0], ps[1]);
        }
        __syncthreads();

        // S = Qs @ K^T  (3-term split-bf16)
        f32x16 s0, s1;
        #pragma unroll
        for (int i = 0; i < 16; ++i) { s0[i] = 0.f; s1[i] = 0.f; }
        #pragma unroll
        for (int ks = 0; ks < 4; ++ks) {
            int kb = ks * 16 + lh * 8;
            s16x8 b0h = ldsfrag(sK + (size_t)lrow * PADK + kb);
            s16x8 b0l = ldsfrag(sK + (size_t)(64 + lrow) * PADK + kb);
            s0 = __builtin_amdgcn_mfma_f32_32x32x16_bf16(qh[ks], b0h, s0, 0, 0, 0);
            s0 = __builtin_amdgcn_mfma_f32_32x32x16_bf16(qh[ks], b0l, s0, 0, 0, 0);
            s0 = __builtin_amdgcn_mfma_f32_32x32x16_bf16(ql[ks], b0h, s0, 0, 0, 0);
            s16x8 b1h = ldsfrag(sK + (size_t)(32 + lrow) * PADK + kb);
            s16x8 b1l = ldsfrag(sK + (size_t)(96 + lrow) * PADK + kb);
            s1 = __builtin_amdgcn_mfma_f32_32x32x16_bf16(qh[ks], b1h, s1, 0, 0, 0);
            s1 = __builtin_amdgcn_mfma_f32_32x32x16_bf16(qh[ks], b1l, s1, 0, 0, 0);
            s1 = __builtin_amdgcn_mfma_f32_32x32x16_bf16(ql[ks], b1h, s1, 0, 0, 0);
        }

        // row max across 32 key-cols (lanes) via packed-f16 butterfly
        union H2I { __half2 h2; int i; } hmx[8];
        #pragma unroll
        for (int j = 0; j < 8; ++j)
            hmx[j].h2 = __floats2half2_rn(fmaxf(s0[2 * j],     s1[2 * j]),
                                          fmaxf(s0[2 * j + 1], s1[2 * j + 1]));
        #pragma unroll
        for (int msk = 1; msk < 32; msk <<= 1) {
            #pragma unroll
            for (int j = 0; j < 8; ++j) {
                int o = __shfl_xor(hmx[j].i, msk, 64);
                hmx[j].i = pkmax_f16(hmx[j].i, o);
            }
        }

        // all waves must be done reading K before P overlays it
        __syncthreads();

        // merged: max-unpack + alpha + rescale + P = exp2(S-m) -> LDS (trunc bf16;
        // truncation bias cancels in O/l since La uses the same bf16 P)
        unsigned short* pp = sK + (size_t)(wv * 32) * PADK;
        #pragma unroll
        for (int j = 0; j < 8; ++j) {
            float rm0 = __low2float(hmx[j].h2), rm1 = __high2float(hmx[j].h2);
            #pragma unroll
            for (int h = 0; h < 2; ++h) {
                int r = 2 * j + h;
                float rm = h ? rm1 : rm0;
                float mn = fmaxf(mrow[r], rm);
                float alf = exp2f(mrow[r] - mn);
                mrow[r] = mn;
                float p0 = exp2f(s0[r] - mn);
                float p1 = exp2f(s1[r] - mn);
                O0[r] *= alf; O1[r] *= alf; La[r] *= alf;
                int row = (r & 3) + 8 * (r >> 2) + 4 * lh;
                pp[row * PADK + lrow]      = f2bf_trunc(p0);
                pp[row * PADK + 32 + lrow] = f2bf_trunc(p1);
            }
        }

        // O += P @ V ; l += P @ 1 (ones-column MFMA replaces shuffle row-sums)
        #pragma unroll
        for (int ks = 0; ks < 4; ++ks) {
            int kb = ks * 16 + lh * 8;
            s16x8 a  = ldsfrag(pp + (size_t)lrow * PADK + kb);
            s16x8 b0 = ldsfrag(sV + (size_t)lrow * PADK + kb);
            s16x8 b1 = ldsfrag(sV + (size_t)(32 + lrow) * PADK + kb);
            O0 = __builtin_amdgcn_mfma_f32_32x32x16_bf16(a, b0,   O0, 0, 0, 0);
            O1 = __builtin_amdgcn_mfma_f32_32x32x16_bf16(a, b1,   O1, 0, 0, 0);
            La = __builtin_amdgcn_mfma_f32_32x32x16_bf16(a, ones, La, 0, 0, 0);
        }
    }

    // store partials
    #pragma unroll
    for (int r = 0; r < 16; ++r) {
        int row = (r & 3) + 8 * (r >> 2) + 4 * lh;
        int grow = q0 + row;
        size_t ob = ((size_t)c * N_SEQ + grow) * 64;
        Opart[ob + lrow]      = O0[r];
        Opart[ob + 32 + lrow] = O1[r];
        if (lrow == 0) {
            mpart[c * N_SEQ + grow] = mrow[r];
            lpart[c * N_SEQ + grow] = La[r];
        }
    }
}

// ---------------- Kernel 4: combine split-K partials (float4) ----------------
__global__ __launch_bounds__(256) void combine(const float* __restrict__ Opart,
                                               const float* __restrict__ mpart,
                                               const float* __restrict__ lpart,
                                               float* __restrict__ out,
                                               int nsplit) {
    int idx = blockIdx.x * 256 + threadIdx.x;    // N_SEQ*16
    int row = idx >> 4, d4 = idx & 15;
    float M = -1e30f;
    for (int c = 0; c < nsplit; ++c) M = fmaxf(M, mpart[c * N_SEQ + row]);
    float4 num = make_float4(0.f, 0.f, 0.f, 0.f);
    float den = 0.f;
    for (int c = 0; c < nsplit; ++c) {
        float w = exp2f(mpart[c * N_SEQ + row] - M);
        den += w * lpart[c * N_SEQ + row];
        float4 o = ((const float4*)Opart)[((size_t)c * N_SEQ + row) * 16 + d4];
        num.x += w * o.x; num.y += w * o.y; num.z += w * o.z; num.w += w * o.w;
    }
    float inv = 1.0f / den;
    num.x *= inv; num.y *= inv; num.z *= inv; num.w *= inv;
    ((float4*)out)[idx] = num;
}

extern "C" void kernel_launch(void* const* d_in, const int* in_sizes, int n_in,
                              void* d_out, int out_size, void* d_ws, size_t ws_size,
                              hipStream_t stream) {
    const float* X  = (const float*)d_in[0];
    const float* WQ = (const float*)d_in[1];
    const float* WK = (const float*)d_in[2];
    const float* WV = (const float*)d_in[3];
    float* out = (float*)d_out;

    // workspace carve
    const size_t szQK = (size_t)N_SEQ * 64 * 2;      // 1 MB each (bf16)
    const size_t szW  = (size_t)192 * E_DIM * 2;     // 288 KB each
    const size_t szX  = (size_t)N_SEQ * E_DIM * 2;   // 12.6 MB each (bf16)
    char* p = (char*)d_ws;
    unsigned short* Qhi = (unsigned short*)p; p += szQK;
    unsigned short* Qlo = (unsigned short*)p; p += szQK;
    unsigned short* Khi = (unsigned short*)p; p += szQK;
    unsigned short* Klo = (unsigned short*)p; p += szQK;
    unsigned short* Vt  = (unsigned short*)p; p += szQK;
    unsigned short* Wthi = (unsigned short*)p; p += szW;
    unsigned short* Wtlo = (unsigned short*)p; p += szW;
    unsigned short* Xhi = (unsigned short*)p; p += szX;
    unsigned short* Xlo = (unsigned short*)p; p += szX;
    size_t base = (size_t)(p - (char*)d_ws);
    size_t per  = (size_t)N_SEQ * 64 * 4 + 2 * (size_t)N_SEQ * 4;  // Opart + m + l per split
    int nsplit = 16;
    while (nsplit > 1 && base + (size_t)nsplit * per > ws_size) nsplit >>= 1;
    float* mpart = (float*)p; p += (size_t)nsplit * N_SEQ * 4;
    float* lpart = (float*)p; p += (size_t)nsplit * N_SEQ * 4;
    float* Opart = (float*)p;

    int chunk = N_SEQ / nsplit;

    prep_w<<<(192 * E_DIM + 255) / 256, 256, 0, stream>>>(WQ, WK, WV, Wthi, Wtlo);
    prep_x<<<(N_SEQ * E_DIM / 4) / 256, 256, 0, stream>>>(X, Xhi, Xlo);
    proj_qkv<<<1536, 256, 0, stream>>>(Xhi, Xlo, Wthi, Wtlo, Qhi, Qlo, Khi, Klo, Vt);
    attn<<<dim3(nsplit, N_SEQ / 128), 256, 0, stream>>>(Qhi, Qlo, Khi, Klo, Vt,
                                                        Opart, mpart, lpart, chunk);
    combine<<<(N_SEQ * 16 + 255) / 256, 256, 0, stream>>>(Opart, mpart, lpart, out, nsplit);
}

// Round 5
// 178.316 us; speedup vs baseline: 1.5492x; 1.2439x over previous
//
#include <hip/hip_runtime.h>
#include <hip/hip_fp16.h>

#define N_SEQ 8192
#define E_DIM 768
#define D_OUT 64
#define PADK 68                       // 64 + 4 pad -> 136B rows: 2-way (free) bank aliasing
#define SCALE_LOG2 0.18033688011112042f   // 1/(8*ln2): fold softmax scale + log2e into Q

typedef __attribute__((ext_vector_type(8)))  short s16x8;
typedef __attribute__((ext_vector_type(4)))  float f32x4;
typedef __attribute__((ext_vector_type(16))) float f32x16;

static __device__ __forceinline__ unsigned short f2bf(float f) {
    union { float f; unsigned int u; } v; v.f = f;
    unsigned int r = v.u + 0x7FFFu + ((v.u >> 16) & 1u);   // RNE
    return (unsigned short)(r >> 16);
}
static __device__ __forceinline__ float bf2f(unsigned short h) {
    union { float f; unsigned int u; } v; v.u = ((unsigned int)h) << 16; return v.f;
}
// pack two f32 -> bf16x2 by truncation (bias cancels: same P feeds O and l)
static __device__ __forceinline__ unsigned int packbf(float a, float b) {
    union { float f; unsigned int u; } x, y; x.f = a; y.f = b;
    return (y.u & 0xFFFF0000u) | (x.u >> 16);
}
static __device__ __forceinline__ s16x8 gfrag(const unsigned short* p) {
    union { uint4 u; s16x8 s; } r; r.u = *(const uint4*)p; return r.s;
}
static __device__ __forceinline__ s16x8 ldsfrag(const unsigned short* p) {
    union { uint2 u[2]; s16x8 s; } r;
    r.u[0] = *(const uint2*)(p);
    r.u[1] = *(const uint2*)(p + 4);
    return r.s;
}
static __device__ __forceinline__ void st32(unsigned short* d, uint4 a, uint4 b) {
    uint2* p = (uint2*)d;
    p[0] = make_uint2(a.x, a.y); p[1] = make_uint2(a.z, a.w);
    p[2] = make_uint2(b.x, b.y); p[3] = make_uint2(b.z, b.w);
}

// ---------------- Kernel 1a: W -> Wt (transposed, bf16 hi/lo) ----------------
__global__ __launch_bounds__(256) void prep_w(const float* __restrict__ WQ,
                                              const float* __restrict__ WK,
                                              const float* __restrict__ WV,
                                              unsigned short* __restrict__ Wthi,
                                              unsigned short* __restrict__ Wtlo) {
    int idx = blockIdx.x * 256 + threadIdx.x;          // 192*768 total
    if (idx >= 192 * E_DIM) return;
    int n = idx / E_DIM;
    int k = idx - n * E_DIM;
    float v;
    if (n < 64)       v = WQ[k * 64 + n];
    else if (n < 128) v = WK[k * 64 + (n - 64)];
    else              v = WV[k * 64 + (n - 128)];
    unsigned short hb = f2bf(v);
    Wthi[idx] = hb;
    Wtlo[idx] = f2bf(v - bf2f(hb));
}

// ---------------- Kernel 1b: X -> bf16 hi/lo (coalesced, BW-bound) -----------
__global__ __launch_bounds__(256) void prep_x(const float* __restrict__ X,
                                              unsigned short* __restrict__ Xhi,
                                              unsigned short* __restrict__ Xlo) {
    int idx = blockIdx.x * 256 + threadIdx.x;          // over float4: 8192*768/4
    float4 v = ((const float4*)X)[idx];
    ushort4 hi, lo;
    hi.x = f2bf(v.x); lo.x = f2bf(v.x - bf2f(hi.x));
    hi.y = f2bf(v.y); lo.y = f2bf(v.y - bf2f(hi.y));
    hi.z = f2bf(v.z); lo.z = f2bf(v.z - bf2f(hi.z));
    hi.w = f2bf(v.w); lo.w = f2bf(v.w - bf2f(hi.w));
    ((ushort4*)Xhi)[idx] = hi;
    ((ushort4*)Xlo)[idx] = lo;
}

// ---------------- Kernel 2: QKV projection (fused Q/K/V per wave) ------------
// Wave computes Q,K,V for one 16-row x 16-col block: X-frags loaded once,
// 7 MFMAs per 32-k step. 512 m-tiles x 4 col-blocks = 2048 wave-tasks.
__global__ __launch_bounds__(256, 4) void proj_qkv(const unsigned short* __restrict__ Xhi,
                                                   const unsigned short* __restrict__ Xlo,
                                                   const unsigned short* __restrict__ Wthi,
                                                   const unsigned short* __restrict__ Wtlo,
                                                   unsigned short* __restrict__ Qhi,
                                                   unsigned short* __restrict__ Qlo,
                                                   unsigned short* __restrict__ Khi,
                                                   unsigned short* __restrict__ Klo,
                                                   unsigned short* __restrict__ Vt) {
    int tid  = threadIdx.x;
    int wv   = tid >> 6;
    int lane = tid & 63;
    int id   = blockIdx.x * 4 + wv;          // 0..2047
    int mt   = id >> 2;
    int c    = id & 3;                       // 16-col block within D=64
    int m0 = mt * 16, n0 = c * 16;
    int lr = lane & 15, lk = lane >> 4;      // row-in-tile, k-quad

    f32x4 aQ, aK, aV;
    #pragma unroll
    for (int i = 0; i < 4; ++i) { aQ[i] = 0.f; aK[i] = 0.f; aV[i] = 0.f; }

    const unsigned short* xh  = Xhi  + (size_t)(m0 + lr) * E_DIM + lk * 8;
    const unsigned short* xl  = Xlo  + (size_t)(m0 + lr) * E_DIM + lk * 8;
    const unsigned short* wqh = Wthi + (size_t)(n0 + lr) * E_DIM + lk * 8;
    const unsigned short* wql = Wtlo + (size_t)(n0 + lr) * E_DIM + lk * 8;
    const unsigned short* wkh = Wthi + (size_t)(64 + n0 + lr) * E_DIM + lk * 8;
    const unsigned short* wkl = Wtlo + (size_t)(64 + n0 + lr) * E_DIM + lk * 8;
    const unsigned short* wvh = Wthi + (size_t)(128 + n0 + lr) * E_DIM + lk * 8;

    #pragma unroll 2
    for (int ks = 0; ks < E_DIM / 32; ++ks) {
        int kb = ks * 32;
        s16x8 ah = gfrag(xh + kb);
        s16x8 al = gfrag(xl + kb);
        s16x8 bqh = gfrag(wqh + kb);
        s16x8 bql = gfrag(wql + kb);
        s16x8 bkh = gfrag(wkh + kb);
        s16x8 bkl = gfrag(wkl + kb);
        s16x8 bvh = gfrag(wvh + kb);
        aQ = __builtin_amdgcn_mfma_f32_16x16x32_bf16(ah, bqh, aQ, 0, 0, 0);
        aK = __builtin_amdgcn_mfma_f32_16x16x32_bf16(ah, bkh, aK, 0, 0, 0);
        aV = __builtin_amdgcn_mfma_f32_16x16x32_bf16(ah, bvh, aV, 0, 0, 0);
        aQ = __builtin_amdgcn_mfma_f32_16x16x32_bf16(ah, bql, aQ, 0, 0, 0);
        aK = __builtin_amdgcn_mfma_f32_16x16x32_bf16(ah, bkl, aK, 0, 0, 0);
        aQ = __builtin_amdgcn_mfma_f32_16x16x32_bf16(al, bqh, aQ, 0, 0, 0);
        aK = __builtin_amdgcn_mfma_f32_16x16x32_bf16(al, bkh, aK, 0, 0, 0);
    }

    // C/D layout (16x16): col = lane&15, row = (lane>>4)*4 + r  [m89/m91]
    #pragma unroll
    for (int r = 0; r < 4; ++r) {
        int grow = m0 + lk * 4 + r, gcol = n0 + lr;
        float q = aQ[r] * SCALE_LOG2;
        unsigned short hb = f2bf(q);
        Qhi[(size_t)grow * 64 + gcol] = hb;
        Qlo[(size_t)grow * 64 + gcol] = f2bf(q - bf2f(hb));
        float v = aK[r];
        hb = f2bf(v);
        Khi[(size_t)grow * 64 + gcol] = hb;
        Klo[(size_t)grow * 64 + gcol] = f2bf(v - bf2f(hb));
    }
    ushort4 pk;                          // V: 4 consecutive rows -> one 8B store
    pk.x = f2bf(aV[0]); pk.y = f2bf(aV[1]);
    pk.z = f2bf(aV[2]); pk.w = f2bf(aV[3]);
    *(ushort4*)(Vt + (size_t)(n0 + lr) * N_SEQ + m0 + lk * 4) = pk;
}

// ---------------- Kernel 3: flash attention (S^T form + prefetch) ------------
// grid (nsplit, 64); block 256 = 4 waves, each wave owns 32 Q-rows.
// S^T = K*Q^T so each query's scores are in-lane: scalar m/l, in-lane max,
// P -> A-frags via lane^32 swap (no LDS round-trip). K/V global loads for
// iter i+1 prefetched into registers during iter i's compute phase.
__global__ __launch_bounds__(256, 3) void attn(const unsigned short* __restrict__ Qhi,
                                               const unsigned short* __restrict__ Qlo,
                                               const unsigned short* __restrict__ Khi,
                                               const unsigned short* __restrict__ Klo,
                                               const unsigned short* __restrict__ Vt,
                                               float* __restrict__ Opart,
                                               float* __restrict__ mpart,
                                               float* __restrict__ lpart,
                                               int chunk) {
    __shared__ unsigned short sK[128 * PADK];   // rows 0-63 Khi, 64-127 Klo
    __shared__ unsigned short sV [64 * PADK];   // [d][key]

    int tid = threadIdx.x, wv = tid >> 6, lane = tid & 63;
    int lrow = lane & 31, lh = lane >> 5;
    int c = blockIdx.x, qb = blockIdx.y;
    int q0 = qb * 128 + wv * 32;

    // Q fragments (whole D=64) resident in registers
    s16x8 qh[4], ql[4];
    #pragma unroll
    for (int ks = 0; ks < 4; ++ks) {
        int kb = ks * 16 + lh * 8;
        qh[ks] = gfrag(Qhi + (size_t)(q0 + lrow) * 64 + kb);
        ql[ks] = gfrag(Qlo + (size_t)(q0 + lrow) * 64 + kb);
    }

    f32x16 O0, O1;
    #pragma unroll
    for (int i = 0; i < 16; ++i) { O0[i] = 0.f; O1[i] = 0.f; }
    float mrow = -1e30f, lrun = 0.f;

    int steps = chunk >> 6;
    int srow = tid >> 2, sseg = tid & 3;    // staging: 64 rows x 4 segs x 16 elems

    // prefetch tile 0
    uint4 rA0, rA1, rB0, rB1, rC0, rC1;
    {
        int j1 = c * chunk;
        const uint4* ps = (const uint4*)(Khi + ((size_t)(j1 + srow) * 64 + sseg * 16));
        rA0 = ps[0]; rA1 = ps[1];
        ps = (const uint4*)(Klo + ((size_t)(j1 + srow) * 64 + sseg * 16));
        rB0 = ps[0]; rB1 = ps[1];
        ps = (const uint4*)(Vt + ((size_t)srow * N_SEQ + j1 + sseg * 16));
        rC0 = ps[0]; rC1 = ps[1];
    }

    for (int it = 0; it < steps; ++it) {
        __syncthreads();                     // all waves done reading prev tile
        st32(sK + srow * PADK + sseg * 16, rA0, rA1);
        st32(sK + (64 + srow) * PADK + sseg * 16, rB0, rB1);
        st32(sV + srow * PADK + sseg * 16, rC0, rC1);
        __syncthreads();

        if (it + 1 < steps) {                // prefetch next tile (waits at next st32)
            int j1 = c * chunk + (it + 1) * 64;
            const uint4* ps = (const uint4*)(Khi + ((size_t)(j1 + srow) * 64 + sseg * 16));
            rA0 = ps[0]; rA1 = ps[1];
            ps = (const uint4*)(Klo + ((size_t)(j1 + srow) * 64 + sseg * 16));
            rB0 = ps[0]; rB1 = ps[1];
            ps = (const uint4*)(Vt + ((size_t)srow * N_SEQ + j1 + sseg * 16));
            rC0 = ps[0]; rC1 = ps[1];
        }

        // S^T = K @ Q^T  (3-term split-bf16): s0 keys 0-31, s1 keys 32-63
        f32x16 s0, s1;
        #pragma unroll
        for (int i = 0; i < 16; ++i) { s0[i] = 0.f; s1[i] = 0.f; }
        #pragma unroll
        for (int ks = 0; ks < 4; ++ks) {
            int kb = ks * 16 + lh * 8;
            s16x8 b0h = ldsfrag(sK + (size_t)lrow * PADK + kb);
            s16x8 b0l = ldsfrag(sK + (size_t)(64 + lrow) * PADK + kb);
            s0 = __builtin_amdgcn_mfma_f32_32x32x16_bf16(b0h, qh[ks], s0, 0, 0, 0);
            s0 = __builtin_amdgcn_mfma_f32_32x32x16_bf16(b0l, qh[ks], s0, 0, 0, 0);
            s0 = __builtin_amdgcn_mfma_f32_32x32x16_bf16(b0h, ql[ks], s0, 0, 0, 0);
            s16x8 b1h = ldsfrag(sK + (size_t)(32 + lrow) * PADK + kb);
            s16x8 b1l = ldsfrag(sK + (size_t)(96 + lrow) * PADK + kb);
            s1 = __builtin_amdgcn_mfma_f32_32x32x16_bf16(b1h, qh[ks], s1, 0, 0, 0);
            s1 = __builtin_amdgcn_mfma_f32_32x32x16_bf16(b1l, qh[ks], s1, 0, 0, 0);
            s1 = __builtin_amdgcn_mfma_f32_32x32x16_bf16(b1h, ql[ks], s1, 0, 0, 0);
        }

        // in-lane row max (this lane's query = lrow; 32 of 64 keys per half)
        float rm = s0[0];
        #pragma unroll
        for (int i = 1; i < 16; ++i) rm = fmaxf(rm, s0[i]);
        #pragma unroll
        for (int i = 0; i < 16; ++i) rm = fmaxf(rm, s1[i]);
        rm = fmaxf(rm, __shfl_xor(rm, 32, 64));
        float mn  = fmaxf(mrow, rm);
        float alf = exp2f(mrow - mn);
        mrow = mn;

        // p = exp2(s - m) in place; partial row-sum
        float psum = 0.f;
        #pragma unroll
        for (int i = 0; i < 16; ++i) { s0[i] = exp2f(s0[i] - mn); psum += s0[i]; }
        #pragma unroll
        for (int i = 0; i < 16; ++i) { s1[i] = exp2f(s1[i] - mn); psum += s1[i]; }
        lrun = lrun * alf + psum;

        // pack P to bf16 pairs; swap halves via lane^32 to build A-frags
        unsigned int I[16], J[16];
        #pragma unroll
        for (int q4 = 0; q4 < 4; ++q4) {
            I[2 * q4]     = packbf(s0[4 * q4],     s0[4 * q4 + 1]);
            I[2 * q4 + 1] = packbf(s0[4 * q4 + 2], s0[4 * q4 + 3]);
            I[8 + 2 * q4]     = packbf(s1[4 * q4],     s1[4 * q4 + 1]);
            I[8 + 2 * q4 + 1] = packbf(s1[4 * q4 + 2], s1[4 * q4 + 3]);
        }
        #pragma unroll
        for (int i = 0; i < 16; ++i) J[i] = (unsigned int)__shfl_xor((int)I[i], 32, 64);
        s16x8 a[4];
        #pragma unroll
        for (int ks = 0; ks < 4; ++ks) {
            int b = (ks >> 1) * 8 + (ks & 1) * 4;
            union { unsigned int u[4]; s16x8 s; } fa;
            fa.u[0] = lh ? J[b + 2] : I[b];
            fa.u[1] = lh ? J[b + 3] : I[b + 1];
            fa.u[2] = lh ? I[b + 2] : J[b];
            fa.u[3] = lh ? I[b + 3] : J[b + 1];
            a[ks] = fa.s;
        }

        // rescale O by alpha of each O-row's query (fetch via bpermute)
        #pragma unroll
        for (int r = 0; r < 16; ++r) {
            int qr = (r & 3) + 8 * (r >> 2) + 4 * lh;
            float af = __shfl(alf, qr, 64);
            O0[r] *= af; O1[r] *= af;
        }

        // O += P @ V
        #pragma unroll
        for (int ks = 0; ks < 4; ++ks) {
            int kb = ks * 16 + lh * 8;
            s16x8 b0 = ldsfrag(sV + (size_t)lrow * PADK + kb);
            s16x8 b1 = ldsfrag(sV + (size_t)(32 + lrow) * PADK + kb);
            O0 = __builtin_amdgcn_mfma_f32_32x32x16_bf16(a[ks], b0, O0, 0, 0, 0);
            O1 = __builtin_amdgcn_mfma_f32_32x32x16_bf16(a[ks], b1, O1, 0, 0, 0);
        }
    }

    // store partials
    #pragma unroll
    for (int r = 0; r < 16; ++r) {
        int row = (r & 3) + 8 * (r >> 2) + 4 * lh;
        int grow = q0 + row;
        size_t ob = ((size_t)c * N_SEQ + grow) * 64;
        Opart[ob + lrow]      = O0[r];
        Opart[ob + 32 + lrow] = O1[r];
    }
    float lfull = lrun + __shfl_xor(lrun, 32, 64);
    if (lane < 32) {
        int grow = q0 + lrow;
        mpart[c * N_SEQ + grow] = mrow;
        lpart[c * N_SEQ + grow] = lfull;
    }
}

// ---------------- Kernel 4: combine split-K partials (float4) ----------------
__global__ __launch_bounds__(256) void combine(const float* __restrict__ Opart,
                                               const float* __restrict__ mpart,
                                               const float* __restrict__ lpart,
                                               float* __restrict__ out,
                                               int nsplit) {
    int idx = blockIdx.x * 256 + threadIdx.x;    // N_SEQ*16
    int row = idx >> 4, d4 = idx & 15;
    float M = -1e30f;
    for (int c = 0; c < nsplit; ++c) M = fmaxf(M, mpart[c * N_SEQ + row]);
    float4 num = make_float4(0.f, 0.f, 0.f, 0.f);
    float den = 0.f;
    for (int c = 0; c < nsplit; ++c) {
        float w = exp2f(mpart[c * N_SEQ + row] - M);
        den += w * lpart[c * N_SEQ + row];
        float4 o = ((const float4*)Opart)[((size_t)c * N_SEQ + row) * 16 + d4];
        num.x += w * o.x; num.y += w * o.y; num.z += w * o.z; num.w += w * o.w;
    }
    float inv = 1.0f / den;
    num.x *= inv; num.y *= inv; num.z *= inv; num.w *= inv;
    ((float4*)out)[idx] = num;
}

extern "C" void kernel_launch(void* const* d_in, const int* in_sizes, int n_in,
                              void* d_out, int out_size, void* d_ws, size_t ws_size,
                              hipStream_t stream) {
    const float* X  = (const float*)d_in[0];
    const float* WQ = (const float*)d_in[1];
    const float* WK = (const float*)d_in[2];
    const float* WV = (const float*)d_in[3];
    float* out = (float*)d_out;

    // workspace carve
    const size_t szQK = (size_t)N_SEQ * 64 * 2;      // 1 MB each (bf16)
    const size_t szW  = (size_t)192 * E_DIM * 2;     // 288 KB each
    const size_t szX  = (size_t)N_SEQ * E_DIM * 2;   // 12.6 MB each (bf16)
    char* p = (char*)d_ws;
    unsigned short* Qhi = (unsigned short*)p; p += szQK;
    unsigned short* Qlo = (unsigned short*)p; p += szQK;
    unsigned short* Khi = (unsigned short*)p; p += szQK;
    unsigned short* Klo = (unsigned short*)p; p += szQK;
    unsigned short* Vt  = (unsigned short*)p; p += szQK;
    unsigned short* Wthi = (unsigned short*)p; p += szW;
    unsigned short* Wtlo = (unsigned short*)p; p += szW;
    unsigned short* Xhi = (unsigned short*)p; p += szX;
    unsigned short* Xlo = (unsigned short*)p; p += szX;
    size_t base = (size_t)(p - (char*)d_ws);
    size_t per  = (size_t)N_SEQ * 64 * 4 + 2 * (size_t)N_SEQ * 4;  // Opart + m + l per split
    int nsplit = 16;
    while (nsplit > 1 && base + (size_t)nsplit * per > ws_size) nsplit >>= 1;
    float* mpart = (float*)p; p += (size_t)nsplit * N_SEQ * 4;
    float* lpart = (float*)p; p += (size_t)nsplit * N_SEQ * 4;
    float* Opart = (float*)p;

    int chunk = N_SEQ / nsplit;

    prep_w<<<(192 * E_DIM + 255) / 256, 256, 0, stream>>>(WQ, WK, WV, Wthi, Wtlo);
    prep_x<<<(N_SEQ * E_DIM / 4) / 256, 256, 0, stream>>>(X, Xhi, Xlo);
    proj_qkv<<<512, 256, 0, stream>>>(Xhi, Xlo, Wthi, Wtlo, Qhi, Qlo, Khi, Klo, Vt);
    attn<<<dim3(nsplit, N_SEQ / 128), 256, 0, stream>>>(Qhi, Qlo, Khi, Klo, Vt,
                                                        Opart, mpart, lpart, chunk);
    combine<<<(N_SEQ * 16 + 255) / 256, 256, 0, stream>>>(Opart, mpart, lpart, out, nsplit);
}